// Round 6
// baseline (9224.709 us; speedup 1.0000x reference)
//
#include <hip/hip_runtime.h>
#include <stdint.h>

// Problem constants
#define NT 1024
#define NB 64
#define ND 128
#define NH 512

typedef float f32x4  __attribute__((ext_vector_type(4)));
typedef short bf16x8 __attribute__((ext_vector_type(8)));
typedef unsigned int uint32x4 __attribute__((ext_vector_type(4)));
typedef unsigned long long u64;

// round-to-nearest-even f32 -> bf16
__device__ __forceinline__ unsigned short f2bf(float f) {
  uint32_t u = __float_as_uint(f);
  u += 0x7fffu + ((u >> 16) & 1u);
  return (unsigned short)(u >> 16);
}

__device__ __forceinline__ bf16x8 cvt8(f32x4 a, f32x4 b) {
  bf16x8 r;
  r[0] = (short)f2bf(a[0]); r[1] = (short)f2bf(a[1]);
  r[2] = (short)f2bf(a[2]); r[3] = (short)f2bf(a[3]);
  r[4] = (short)f2bf(b[0]); r[5] = (short)f2bf(b[1]);
  r[6] = (short)f2bf(b[2]); r[7] = (short)f2bf(b[3]);
  return r;
}

// Persistent RNN kernel — R3's replay-proven LL-tag protocol (intrinsic
// relaxed agent-scope atomics, no asm, no XCD claim) with two structural
// fixes for the TCC-transaction storm R3's counters showed:
//   (a) consumer-coalesced llbuf layout [slot][rg][kk][j][lane]: every poll
//       load instruction covers a lane-contiguous 512B span (4 L2 lines)
//       instead of 16 scattered 128B segments;
//   (b) 8 WGs x 1024 threads (16 waves): wave wv stages exactly one K-chunk
//       (kk = wv), so a poll round is 4 loads, and only 2 WGs (not 8) share
//       a row group -> 4x less redundant fr traffic.
// WG wg: rg = wg>>1 (16 batch rows), cgh = wg&1 (256 hidden cols). Wave wv
// owns a 16x16 C tile (cols cgh*256 + wv*16 + col). W_hid/W_in B-frags are
// stationary in VGPRs. fr moves via llbuf (2 slots) of 8B units
// [tag:32 | bf16 pair:32]; tag t == "this is fr_t" (naturally-atomic 8B
// stores -> no tearing). WAR safety: each WG's 16 waves collectively poll
// all 16 chunks (all 32 producer waves of the rg) for tag t before the
// step-t barrier, and publishes (tag t+1, overwriting tag t-1 data) follow
// that barrier -> every reader of tag t-1 data provably finished.
__global__ __launch_bounds__(1024, 1) void rnn_persistent(
    const float* __restrict__ input,   // [T,B,D]
    const float* __restrict__ W_in,    // [H,D]
    const float* __restrict__ b_in,    // [H]
    const float* __restrict__ W_hid,   // [H,H]
    const float* __restrict__ b_hid,   // [H]
    float* __restrict__ out,           // [T,B,H] fp32
    u64* __restrict__ llbuf)           // 2 slots x 16384 units x 8B = 256 KB
{
  __shared__ uint32x4 lds[2][16][64];  // [slot][chunk][lane] payloads, 32 KB

  const int wg   = blockIdx.x;   // 0..7
  const int rg   = wg >> 1;      // row group 0..3 (16 batch rows)
  const int cgh  = wg & 1;       // col half 0..1 (256 hidden cols)
  const int tid  = threadIdx.x;
  const int wv   = tid >> 6;     // wave 0..15
  const int lane = tid & 63;
  const int col  = lane & 15;
  const int quad = lane >> 4;
  const int kq   = quad * 8;

  const int bA = rg * 16 + col;             // A-frag batch row / staged row
  const int gB = cgh * 256 + wv * 16 + col; // B-frag / C column
  const int bC = rg * 16 + quad * 4;        // C rows: bC + r

  // ---- stationary weights: B-fragments in registers (bf16) ----
  bf16x8 Bh[16];
#pragma unroll
  for (int kk = 0; kk < 16; ++kk) {
    const float* p = W_hid + (size_t)gB * NH + kk * 32 + kq;
    Bh[kk] = cvt8(*(const f32x4*)p, *(const f32x4*)(p + 4));
  }
  bf16x8 Bi[4];
#pragma unroll
  for (int kk = 0; kk < 4; ++kk) {
    const float* p = W_in + (size_t)gB * ND + kk * 32 + kq;
    Bi[kk] = cvt8(*(const f32x4*)p, *(const f32x4*)(p + 4));
  }
  const float blane = b_hid[gB] + b_in[gB];

  // ---- communication addressing (unit = 8B; slot stride 16384 units) ----
  // unit index = ((rg*16 + kk)*4 + j)*64 + (pairquad*16 + rowcol)
  // holds pair p = kk*16 + pairquad*4 + j (cols 2p,2p+1) of row rg*16+rowcol.
  // consumer (stager): wave wv reads chunk kk=wv, j=0..3, at its own lane.
  const u64* cons0 = llbuf + (size_t)((rg * 16 + wv) * 256 + lane);
  // producer: even lanes handle pair P = gB/2 for rows bC..bC+3
  // (consecutive units).
  const int P = cgh * 128 + wv * 8 + (col >> 1);
  u64* prod0 = llbuf + (size_t)(((rg * 16 + (P >> 4)) * 4 + (P & 3)) * 64 +
                                ((P >> 2) & 3) * 16 + quad * 4);

  float v0 = 0.f, v1 = 0.f, v2 = 0.f, v3 = 0.f;
  u64 u0 = 0, u1 = 0, u2 = 0, u3 = 0;
  int dead = 0;  // hang-guard latch; cannot trigger in normal operation

#pragma unroll 1
  for (int t = 0; t < NT; ++t) {
    const u64* cb = cons0 + (size_t)(t & 1) * 16384;

    // issue this step's poll FIRST (minimizes detect latency)
    if (t > 0) {
      u0 = __hip_atomic_load(cb,       __ATOMIC_RELAXED, __HIP_MEMORY_SCOPE_AGENT);
      u1 = __hip_atomic_load(cb + 64,  __ATOMIC_RELAXED, __HIP_MEMORY_SCOPE_AGENT);
      u2 = __hip_atomic_load(cb + 128, __ATOMIC_RELAXED, __HIP_MEMORY_SCOPE_AGENT);
      u3 = __hip_atomic_load(cb + 192, __ATOMIC_RELAXED, __HIP_MEMORY_SCOPE_AGENT);
    }

    // input slice + projection MFMAs (independent of fr; overlaps the poll)
    const float* ip = input + ((size_t)t * NB + bA) * ND + kq;
    f32x4 x0 = *(const f32x4*)(ip);
    f32x4 x1 = *(const f32x4*)(ip + 4);
    f32x4 x2 = *(const f32x4*)(ip + 32);
    f32x4 x3 = *(const f32x4*)(ip + 36);
    f32x4 x4 = *(const f32x4*)(ip + 64);
    f32x4 x5 = *(const f32x4*)(ip + 68);
    f32x4 x6 = *(const f32x4*)(ip + 96);
    f32x4 x7 = *(const f32x4*)(ip + 100);

    f32x4 acc = {0.f, 0.f, 0.f, 0.f};
    acc = __builtin_amdgcn_mfma_f32_16x16x32_bf16(cvt8(x0, x1), Bi[0], acc, 0, 0, 0);
    acc = __builtin_amdgcn_mfma_f32_16x16x32_bf16(cvt8(x2, x3), Bi[1], acc, 0, 0, 0);
    acc = __builtin_amdgcn_mfma_f32_16x16x32_bf16(cvt8(x4, x5), Bi[2], acc, 0, 0, 0);
    acc = __builtin_amdgcn_mfma_f32_16x16x32_bf16(cvt8(x6, x7), Bi[3], acc, 0, 0, 0);

    if (t > 0) {
      // spin until this wave's 4 units all carry tag t (usually 0-2 retries)
      const int lim = dead ? 0 : (1 << 20);
      int tries = 0;
      while ((((uint32_t)(u0 >> 32) ^ (uint32_t)t) |
              ((uint32_t)(u1 >> 32) ^ (uint32_t)t) |
              ((uint32_t)(u2 >> 32) ^ (uint32_t)t) |
              ((uint32_t)(u3 >> 32) ^ (uint32_t)t)) != 0 &&
             tries < lim) {
        ++tries;
        __builtin_amdgcn_s_sleep(1);
        u0 = __hip_atomic_load(cb,       __ATOMIC_RELAXED, __HIP_MEMORY_SCOPE_AGENT);
        u1 = __hip_atomic_load(cb + 64,  __ATOMIC_RELAXED, __HIP_MEMORY_SCOPE_AGENT);
        u2 = __hip_atomic_load(cb + 128, __ATOMIC_RELAXED, __HIP_MEMORY_SCOPE_AGENT);
        u3 = __hip_atomic_load(cb + 192, __ATOMIC_RELAXED, __HIP_MEMORY_SCOPE_AGENT);
      }
      if (tries >= (1 << 20)) dead = 1;  // fail visibly, never hang

      // deposit this wave's chunk (kk = wv) — one b128 LDS write per lane
      uint32x4 pay = {(uint32_t)u0, (uint32_t)u1, (uint32_t)u2, (uint32_t)u3};
      lds[t & 1][wv][lane] = pay;
      __syncthreads();
      // recurrent MFMAs: A-frags from LDS (lane-contiguous, conflict-free)
#pragma unroll
      for (int kk = 0; kk < 16; ++kk) {
        uint32x4 p = lds[t & 1][kk][lane];
        acc = __builtin_amdgcn_mfma_f32_16x16x32_bf16(
            __builtin_bit_cast(bf16x8, p), Bh[kk], acc, 0, 0, 0);
      }
    }

    // v = 0.9 v + 0.1 (S + b); fr = relu(v)
    v0 = 0.9f * v0 + 0.1f * (acc[0] + blane);
    v1 = 0.9f * v1 + 0.1f * (acc[1] + blane);
    v2 = 0.9f * v2 + 0.1f * (acc[2] + blane);
    v3 = 0.9f * v3 + 0.1f * (acc[3] + blane);
    float f0 = fmaxf(v0, 0.f), f1 = fmaxf(v1, 0.f);
    float f2 = fmaxf(v2, 0.f), f3 = fmaxf(v3, 0.f);

    // stream output (fp32, plain stores; every (t,b,g) written exactly once)
    float* op = out + ((size_t)t * NB + bC) * NH + gB;
    op[0]      = f0;
    op[NH]     = f1;
    op[2 * NH] = f2;
    op[3 * NH] = f3;

    // publish fr_{t+1}: pair with neighbor lane (cols gB, gB^1); even lanes
    // store 4 consecutive tagged units (rows bC..bC+3, one L2 line)
    float p0 = __shfl_xor(f0, 1, 64);
    float p1 = __shfl_xor(f1, 1, 64);
    float p2 = __shfl_xor(f2, 1, 64);
    float p3 = __shfl_xor(f3, 1, 64);
    if (!(lane & 1)) {
      const u64 tagw = ((u64)(uint32_t)(t + 1)) << 32;
      u64 w0 = tagw | (u64)((uint32_t)f2bf(f0) | ((uint32_t)f2bf(p0) << 16));
      u64 w1 = tagw | (u64)((uint32_t)f2bf(f1) | ((uint32_t)f2bf(p1) << 16));
      u64 w2 = tagw | (u64)((uint32_t)f2bf(f2) | ((uint32_t)f2bf(p2) << 16));
      u64 w3 = tagw | (u64)((uint32_t)f2bf(f3) | ((uint32_t)f2bf(p3) << 16));
      u64* pb = prod0 + (size_t)((t + 1) & 1) * 16384;
      __hip_atomic_store(pb,     w0, __ATOMIC_RELAXED, __HIP_MEMORY_SCOPE_AGENT);
      __hip_atomic_store(pb + 1, w1, __ATOMIC_RELAXED, __HIP_MEMORY_SCOPE_AGENT);
      __hip_atomic_store(pb + 2, w2, __ATOMIC_RELAXED, __HIP_MEMORY_SCOPE_AGENT);
      __hip_atomic_store(pb + 3, w3, __ATOMIC_RELAXED, __HIP_MEMORY_SCOPE_AGENT);
    }
  }
}

extern "C" void kernel_launch(void* const* d_in, const int* in_sizes, int n_in,
                              void* d_out, int out_size, void* d_ws, size_t ws_size,
                              hipStream_t stream) {
  const float* input = (const float*)d_in[0];  // [T,B,D]
  const float* W_in  = (const float*)d_in[1];  // [H,D]
  const float* b_in  = (const float*)d_in[2];  // [H]
  const float* W_hid = (const float*)d_in[3];  // [H,H]
  const float* b_hid = (const float*)d_in[4];  // [H]
  float* out = (float*)d_out;

  // workspace: llbuf 2 slots x 16384 u64 = 256 KB. Harness 0xAA poison gives
  // tag 0xAAAAAAAA != any t in [1,1024] -> consumers block until real data;
  // no initialization launch needed.
  u64* llbuf = (u64*)d_ws;

  hipLaunchKernelGGL(rnn_persistent, dim3(8), dim3(1024), 0, stream,
                     input, W_in, b_in, W_hid, b_hid, out, llbuf);
}